// Round 11
// baseline (385.468 us; speedup 1.0000x reference)
//
#include <hip/hip_runtime.h>

typedef _Float16 h16;
typedef __attribute__((ext_vector_type(8))) _Float16 half8;
typedef __attribute__((ext_vector_type(4))) _Float16 half4;
typedef __attribute__((ext_vector_type(4))) float f32x4;
typedef __attribute__((ext_vector_type(16))) float f32x16;

// weight fragment offsets in d_ws (fp16 elements) — identical to R10
constexpr size_t OFF_P0 = 0;        // [64 ][256]
constexpr size_t OFF_P1 = 16384;    // [256][256]
constexpr size_t OFF_P2 = 81920;
constexpr size_t OFF_P3 = 147456;
constexpr size_t OFF_P4 = 212992;
constexpr size_t OFF_P5 = 278528;   // [320][256] (rows 0..63 ep-part w/ zero row 63, 64..319 h-part)
constexpr size_t OFF_P6 = 360448;
constexpr size_t OFF_P7 = 425984;
constexpr size_t OFF_FEAT = 491520; // [256][256]
constexpr size_t OFF_VIEWS = 557056;// [288][128] (zero rows 283..287)

__device__ __forceinline__ f32x16 mfma32(half8 a, half8 b, f32x16 c) {
  return __builtin_amdgcn_mfma_f32_32x32x16_f16(a, b, c, 0, 0, 0);
}
__device__ __forceinline__ half8 ldfrag(const h16* __restrict__ base, int frag, int l) {
  return *(const half8*)(base + (size_t)frag * 512 + (size_t)l * 8);
}
__device__ __forceinline__ half8 ldsfrag(const h16* __restrict__ base, int frag, int l) {
  return *(const half8*)(base + frag * 512 + l * 8);
}

// fp32 [K][N] row-major -> pre-swizzled fp16 fragments for 32x32x16 (unchanged from R10).
__global__ void convw_kernel(const float* __restrict__ src, h16* __restrict__ dst,
                             int Ksrc, int N, int Kp, int p, int npad) {
  int t = blockIdx.x * 256 + threadIdx.x;
  int nfrags = (Kp >> 4) * (N >> 5);
  int frag = t >> 6;
  if (frag >= nfrags) return;
  int l = t & 63;
  int ntiles = N >> 5;
  int kt = frag / ntiles;
  int nt = frag - kt * ntiles;
  int col = nt * 32 + (l & 31);
  int kbase = kt * 16 + (l >> 5) * 8;
  half8 v;
#pragma unroll
  for (int j = 0; j < 8; ++j) {
    int k = kbase + j;
    float x = 0.f;
    if (k < p) {
      x = src[(size_t)k * N + col];
    } else if (k >= p + npad) {
      int r = k - npad;
      if (r < Ksrc) x = src[(size_t)r * N + col];
    }
    v[j] = (h16)x;
  }
  *(half8*)(dst + (size_t)frag * 512 + (size_t)l * 8) = v;
}

struct Params {
  const float* pts;
  const float* views;
  const h16* wf;
  const float* pb[8];
  const float* views_b;
  const float* feat_b;
  const float* alpha_w;
  const float* alpha_b;
  const float* rgb_w;
  const float* rgb_b;
  float* out;
};

// Epilogue: one 32x32 tile -> frag-major LDS (HW-verified in R8/R9).
// Element (row,col): frag=(row>>5)*16+(col>>4), slot=(row&31)+32*((col>>3)&1), elem=col&7.
template <bool RELU>
__device__ __forceinline__ void epiW(h16* __restrict__ Y, const f32x16& A,
                                     int rt, int ct, const float* __restrict__ bias,
                                     int lr, int lh) {
#pragma unroll
  for (int g = 0; g < 4; ++g) {
    int col0 = ct * 32 + g * 8 + lh * 4;
    f32x4 bv = *(const f32x4*)(bias + col0);
    half4 pk;
#pragma unroll
    for (int i = 0; i < 4; ++i) {
      float v = A[g * 4 + i] + bv[i];
      if (RELU) v = fmaxf(v, 0.f);
      pk[i] = (h16)v;
    }
    *(half4*)(Y + (rt * 16 + ct * 2 + (g >> 1)) * 512 + ((g & 1) * 32 + lr) * 8 + lh * 4) = pk;
  }
}

// embed value for column c given a point (x0,x1,x2)
__device__ __forceinline__ float embed_col(int c, float x0, float x1, float x2) {
  if (c < 3) return c == 0 ? x0 : (c == 1 ? x1 : x2);
  if (c >= 63) return 0.f;
  int t = c - 3;
  int f = t / 6, rem = t - f * 6;
  int d = rem >= 3 ? rem - 3 : rem;
  float x = (d == 0 ? x0 : (d == 1 ? x1 : x2)) * (float)(1 << f);
  return (rem < 3) ? sinf(x) : cosf(x);
}

// One M=64, N=256 layer, in-place on frag-major h [rt*16+kt] (rt 0..1).
// Wave w owns col-tile ct=w. acc = 2 x f32x16 (rt 0 and 1).
// EXTEP (L5, K=320): weight frags 0..3 pair with ep frags; h-part uses WKT0=4 offset.
template <bool RELU, bool EXTEP, int WKT0>
__device__ __forceinline__ void layerF(h16* __restrict__ h, const h16* __restrict__ ep,
                                       const h16* __restrict__ wcur,
                                       const float* __restrict__ bias,
                                       int w, int l, int lr, int lh) {
  f32x16 a0 = (f32x16)0.f, a1 = (f32x16)0.f;
#pragma unroll
  for (int kt = 0; kt < 16; ++kt) {
    half8 x0 = ldsfrag(h, kt, l);
    half8 x1 = ldsfrag(h, 16 + kt, l);
    half8 b = ldfrag(wcur, (WKT0 + kt) * 8 + w, l);
    a0 = mfma32(b, x0, a0);
    a1 = mfma32(b, x1, a1);
  }
  if (EXTEP) {
#pragma unroll
    for (int j = 0; j < 4; ++j) {
      half8 x0 = ldsfrag(ep, j, l);
      half8 x1 = ldsfrag(ep, 4 + j, l);
      half8 b = ldfrag(wcur, j * 8 + w, l);
      a0 = mfma32(b, x0, a0);
      a1 = mfma32(b, x1, a1);
    }
  }
  __syncthreads();  // all reads of h complete before in-place overwrite
  epiW<RELU>(h, a0, 0, w, bias, lr, lh);
  epiW<RELU>(h, a1, 1, w, bias, lr, lh);
  __syncthreads();
}

__global__ __launch_bounds__(512, 6) void nerf_kernel(Params P) {
  __shared__ __align__(16) h16 h[32 * 512];   // 32 KB, frag-major [rt*16 + kt]
  __shared__ __align__(16) h16 ep[8 * 512];   // 8 KB, frag-major [rt*4 + kt]
  __shared__ __align__(16) h16 evp[32];       // 1 ray
  __shared__ float alpha_s[64];

  const int tid = threadIdx.x;
  const int w = tid >> 6, l = tid & 63;
  const int lr = l & 31, lh = l >> 5;
  const int ray = blockIdx.x;
  const h16* wf = P.wf;

  // ---- embeddings -> ep (frag-major). thread (s=tid>>3, q=tid&7): 8 cols ----
  {
    const int s = tid >> 3, q = tid & 7;
    const float* ps = P.pts + ((size_t)ray * 64 + s) * 3;
    const float x0 = ps[0], x1 = ps[1], x2 = ps[2];
    half8 v;
#pragma unroll
    for (int j = 0; j < 8; ++j)
      v[j] = (h16)embed_col(q * 8 + j, x0, x1, x2);
    *(half8*)(ep + ((s >> 5) * 4 + (q >> 1)) * 512 + ((s & 31) + 32 * (q & 1)) * 8) = v;
  }
  if (tid < 32) {
    const int idx = tid;
    float v = 0.f;
    if (idx < 27) {
      if (idx < 3) {
        v = P.views[(size_t)ray * 3 + idx];
      } else {
        const int f = (idx - 3) / 6, rem = (idx - 3) % 6, d = rem % 3;
        const float x = P.views[(size_t)ray * 3 + d] * (float)(1 << f);
        v = (rem < 3) ? sinf(x) : cosf(x);
      }
    }
    evp[idx] = (h16)v;
  }
  __syncthreads();

  // ---- L0: K=64 from ep frags ----
  {
    f32x16 a0 = (f32x16)0.f, a1 = (f32x16)0.f;
#pragma unroll
    for (int kt = 0; kt < 4; ++kt) {
      half8 x0 = ldsfrag(ep, kt, l);
      half8 x1 = ldsfrag(ep, 4 + kt, l);
      half8 b = ldfrag(wf + OFF_P0, kt * 8 + w, l);
      a0 = mfma32(b, x0, a0);
      a1 = mfma32(b, x1, a1);
    }
    epiW<true>(h, a0, 0, w, P.pb[0], lr, lh);
    epiW<true>(h, a1, 1, w, P.pb[0], lr, lh);
    __syncthreads();
  }

  // ---- trunk L1..L7 (in-place) ----
  layerF<true, false, 0>(h, ep, wf + OFF_P1, P.pb[1], w, l, lr, lh);
  layerF<true, false, 0>(h, ep, wf + OFF_P2, P.pb[2], w, l, lr, lh);
  layerF<true, false, 0>(h, ep, wf + OFF_P3, P.pb[3], w, l, lr, lh);
  layerF<true, false, 0>(h, ep, wf + OFF_P4, P.pb[4], w, l, lr, lh);
  layerF<true, true, 4>(h, ep, wf + OFF_P5, P.pb[5], w, l, lr, lh);  // K=320 skip
  layerF<true, false, 0>(h, ep, wf + OFF_P6, P.pb[6], w, l, lr, lh);
  layerF<true, false, 0>(h, ep, wf + OFF_P7, P.pb[7], w, l, lr, lh);

  // ---- alpha = h @ alpha_w + alpha_b (frag-major reads, all 512 threads) ----
  {
    const int s = tid >> 3, q = tid & 7;
    float sum = 0.f;
#pragma unroll
    for (int j = 0; j < 4; ++j) {
      int k0 = q * 32 + j * 8;
      half8 hv = *(const half8*)(h + ((s >> 5) * 16 + (k0 >> 4)) * 512 +
                                 ((s & 31) + 32 * ((k0 >> 3) & 1)) * 8);
      f32x4 w0 = *(const f32x4*)(P.alpha_w + k0);
      f32x4 w1 = *(const f32x4*)(P.alpha_w + k0 + 4);
      sum += (float)hv[0] * w0[0] + (float)hv[1] * w0[1] + (float)hv[2] * w0[2] + (float)hv[3] * w0[3];
      sum += (float)hv[4] * w1[0] + (float)hv[5] * w1[1] + (float)hv[6] * w1[2] + (float)hv[7] * w1[3];
    }
    sum += __shfl_xor(sum, 1);
    sum += __shfl_xor(sum, 2);
    sum += __shfl_xor(sum, 4);
    if (q == 0) alpha_s[s] = sum + P.alpha_b[0];
  }

  // ---- feature = h @ feat_w + feat_b (no relu), in place ----
  layerF<false, false, 0>(h, ep, wf + OFF_FEAT, P.feat_b, w, l, lr, lh);

  // ---- h2 = relu([feature, ev] @ views_w + views_b) -> h cols 0..127 ----
  // all 8 waves: rt = w>>2, ct = w&3 (N=128 -> 4 col-tiles, weights read 2x).
  {
    const int rt = w >> 2, ct = w & 3;
    const h16* wV = wf + OFF_VIEWS;
    f32x16 acc = (f32x16)0.f;
#pragma unroll
    for (int kt = 0; kt < 16; ++kt) {
      half8 x = ldsfrag(h, rt * 16 + kt, l);
      half8 b = ldfrag(wV, kt * 4 + ct, l);
      acc = mfma32(b, x, acc);
    }
#pragma unroll
    for (int kt = 16; kt < 18; ++kt) {
      half8 x = *(const half8*)(evp + (kt - 16) * 16 + lh * 8);  // broadcast row
      half8 b = ldfrag(wV, kt * 4 + ct, l);
      acc = mfma32(b, x, acc);
    }
    __syncthreads();  // h (feature) reads complete
    epiW<true>(h, acc, rt, ct, P.views_b, lr, lh);
    __syncthreads();
  }

  // ---- rgb + output (all 512 threads) ----
  {
    const int s = tid >> 3, q = tid & 7;
    float r0 = 0.f, r1 = 0.f, r2 = 0.f;
#pragma unroll
    for (int j = 0; j < 2; ++j) {
      int k0 = q * 16 + j * 8;
      half8 hv = *(const half8*)(h + ((s >> 5) * 16 + (k0 >> 4)) * 512 +
                                 ((s & 31) + 32 * ((k0 >> 3) & 1)) * 8);
#pragma unroll
      for (int i = 0; i < 8; ++i) {
        const float f = (float)hv[i];
        r0 += f * P.rgb_w[(k0 + i) * 3 + 0];
        r1 += f * P.rgb_w[(k0 + i) * 3 + 1];
        r2 += f * P.rgb_w[(k0 + i) * 3 + 2];
      }
    }
    r0 += __shfl_xor(r0, 1); r0 += __shfl_xor(r0, 2); r0 += __shfl_xor(r0, 4);
    r1 += __shfl_xor(r1, 1); r1 += __shfl_xor(r1, 2); r1 += __shfl_xor(r1, 4);
    r2 += __shfl_xor(r2, 1); r2 += __shfl_xor(r2, 2); r2 += __shfl_xor(r2, 4);
    if (q == 0) {
      float4 o;
      o.x = r0 + P.rgb_b[0];
      o.y = r1 + P.rgb_b[1];
      o.z = r2 + P.rgb_b[2];
      o.w = alpha_s[s];
      *(float4*)(P.out + ((size_t)ray * 64 + s) * 4) = o;
    }
  }
}

extern "C" void kernel_launch(void* const* d_in, const int* in_sizes, int n_in,
                              void* d_out, int out_size, void* d_ws, size_t ws_size,
                              hipStream_t stream) {
  h16* wsw = (h16*)d_ws;
  auto conv = [&](int idx, int Ksrc, int N, int Kp, int p, int npad, size_t off) {
    int nfrags = (Kp / 16) * (N / 32);
    int total = nfrags * 64;
    convw_kernel<<<(total + 255) / 256, 256, 0, stream>>>(
        (const float*)d_in[idx], wsw + off, Ksrc, N, Kp, p, npad);
  };
  conv(2, 63, 256, 64, 63, 1, OFF_P0);
  conv(4, 256, 256, 256, 256, 0, OFF_P1);
  conv(6, 256, 256, 256, 256, 0, OFF_P2);
  conv(8, 256, 256, 256, 256, 0, OFF_P3);
  conv(10, 256, 256, 256, 256, 0, OFF_P4);
  conv(12, 319, 256, 320, 63, 1, OFF_P5);
  conv(14, 256, 256, 256, 256, 0, OFF_P6);
  conv(16, 256, 256, 256, 256, 0, OFF_P7);
  conv(20, 256, 256, 256, 256, 0, OFF_FEAT);
  conv(18, 283, 128, 288, 283, 5, OFF_VIEWS);

  Params P;
  P.pts = (const float*)d_in[0];
  P.views = (const float*)d_in[1];
  P.wf = wsw;
  for (int i = 0; i < 8; ++i) P.pb[i] = (const float*)d_in[3 + 2 * i];
  P.views_b = (const float*)d_in[19];
  P.feat_b = (const float*)d_in[21];
  P.alpha_w = (const float*)d_in[22];
  P.alpha_b = (const float*)d_in[23];
  P.rgb_w = (const float*)d_in[24];
  P.rgb_b = (const float*)d_in[25];
  P.out = (float*)d_out;

  nerf_kernel<<<4096, 512, 0, stream>>>(P);
}

// Round 12
// 370.041 us; speedup vs baseline: 1.0417x; 1.0417x over previous
//
#include <hip/hip_runtime.h>

typedef _Float16 h16;
typedef __attribute__((ext_vector_type(8))) _Float16 half8;
typedef __attribute__((ext_vector_type(4))) _Float16 half4;
typedef __attribute__((ext_vector_type(4))) float f32x4;
typedef __attribute__((ext_vector_type(16))) float f32x16;

// weight fragment offsets in d_ws (fp16 elements) — identical to R10/R11
constexpr size_t OFF_P0 = 0;        // [64 ][256]
constexpr size_t OFF_P1 = 16384;    // [256][256]
constexpr size_t OFF_P2 = 81920;
constexpr size_t OFF_P3 = 147456;
constexpr size_t OFF_P4 = 212992;
constexpr size_t OFF_P5 = 278528;   // [320][256] (rows 0..63 ep-part w/ zero row 63, 64..319 h-part)
constexpr size_t OFF_P6 = 360448;
constexpr size_t OFF_P7 = 425984;
constexpr size_t OFF_FEAT = 491520; // [256][256]
constexpr size_t OFF_VIEWS = 557056;// [288][128] (zero rows 283..287)

__device__ __forceinline__ f32x16 mfma32(half8 a, half8 b, f32x16 c) {
  return __builtin_amdgcn_mfma_f32_32x32x16_f16(a, b, c, 0, 0, 0);
}
__device__ __forceinline__ half8 ldfrag(const h16* __restrict__ base, int frag, int l) {
  return *(const half8*)(base + (size_t)frag * 512 + (size_t)l * 8);
}
__device__ __forceinline__ half8 ldsfrag(const h16* __restrict__ base, int frag, int l) {
  return *(const half8*)(base + frag * 512 + l * 8);
}

// fp32 [K][N] row-major -> pre-swizzled fp16 fragments for 32x32x16 (unchanged).
__global__ void convw_kernel(const float* __restrict__ src, h16* __restrict__ dst,
                             int Ksrc, int N, int Kp, int p, int npad) {
  int t = blockIdx.x * 256 + threadIdx.x;
  int nfrags = (Kp >> 4) * (N >> 5);
  int frag = t >> 6;
  if (frag >= nfrags) return;
  int l = t & 63;
  int ntiles = N >> 5;
  int kt = frag / ntiles;
  int nt = frag - kt * ntiles;
  int col = nt * 32 + (l & 31);
  int kbase = kt * 16 + (l >> 5) * 8;
  half8 v;
#pragma unroll
  for (int j = 0; j < 8; ++j) {
    int k = kbase + j;
    float x = 0.f;
    if (k < p) {
      x = src[(size_t)k * N + col];
    } else if (k >= p + npad) {
      int r = k - npad;
      if (r < Ksrc) x = src[(size_t)r * N + col];
    }
    v[j] = (h16)x;
  }
  *(half8*)(dst + (size_t)frag * 512 + (size_t)l * 8) = v;
}

struct Params {
  const float* pts;
  const float* views;
  const h16* wf;
  const float* pb[8];
  const float* views_b;
  const float* feat_b;
  const float* alpha_w;
  const float* alpha_b;
  const float* rgb_w;
  const float* rgb_b;
  float* out;
};

// Epilogue: one 32x32 tile -> frag-major LDS (HW-verified R8..R11).
// Element (row,col): frag=(row>>5)*16+(col>>4), slot=(row&31)+32*((col>>3)&1), elem=col&7.
template <bool RELU>
__device__ __forceinline__ void epiW(h16* __restrict__ Y, const f32x16& A,
                                     int rt, int ct, const float* __restrict__ bias,
                                     int lr, int lh) {
#pragma unroll
  for (int g = 0; g < 4; ++g) {
    int col0 = ct * 32 + g * 8 + lh * 4;
    f32x4 bv = *(const f32x4*)(bias + col0);
    half4 pk;
#pragma unroll
    for (int i = 0; i < 4; ++i) {
      float v = A[g * 4 + i] + bv[i];
      if (RELU) v = fmaxf(v, 0.f);
      pk[i] = (h16)v;
    }
    *(half4*)(Y + (rt * 16 + ct * 2 + (g >> 1)) * 512 + ((g & 1) * 32 + lr) * 8 + lh * 4) = pk;
  }
}

// embed value for column c given a point (x0,x1,x2)
__device__ __forceinline__ float embed_col(int c, float x0, float x1, float x2) {
  if (c < 3) return c == 0 ? x0 : (c == 1 ? x1 : x2);
  if (c >= 63) return 0.f;
  int t = c - 3;
  int f = t / 6, rem = t - f * 6;
  int d = rem >= 3 ? rem - 3 : rem;
  float x = (d == 0 ? x0 : (d == 1 ? x1 : x2)) * (float)(1 << f);
  return (rem < 3) ? sinf(x) : cosf(x);
}

// One M=64, N=256 layer, in-place on frag-major h [rt*16+kt] (rt 0..1).
// Wave w owns col-tile ct=w. Depth-4 weight ring wr[4] (in on entry: frags
// 0..3 of wcur for this wave); loop-tail refills stream frags 4..KT-1 and then
// the NEXT layer's frags 0..3 (ldfrag(wnextp, j*nstride)) — the barrier's
// vmcnt(0) drain completes them during the epilogue.
// EXTEP (L5, K=320): iterations 0..3 take A from ep (weight rows 0..63 are the
// ep-part incl. zero row 63); iterations 4..19 take A from h.
template <int KT, bool EXTEP, bool RELU>
__device__ __forceinline__ void layerF(h16* __restrict__ h, const h16* __restrict__ ep,
                                       const h16* __restrict__ wcur,
                                       const h16* __restrict__ wnextp, int nstride,
                                       const float* __restrict__ bias,
                                       half8 (&wr)[4],
                                       int w, int l, int lr, int lh) {
  f32x16 a0 = (f32x16)0.f, a1 = (f32x16)0.f;
#pragma unroll
  for (int i = 0; i < KT; ++i) {
    half8 x0, x1;
    if (EXTEP && i < 4) {
      x0 = ldsfrag(ep, i, l);
      x1 = ldsfrag(ep, 4 + i, l);
    } else {
      const int kt = EXTEP ? i - 4 : i;
      x0 = ldsfrag(h, kt, l);
      x1 = ldsfrag(h, 16 + kt, l);
    }
    half8 b = wr[i & 3];
    if (i + 4 < KT)
      wr[i & 3] = ldfrag(wcur, (i + 4) * 8 + w, l);
    else
      wr[i & 3] = ldfrag(wnextp, (i + 4 - KT) * nstride, l);
    a0 = mfma32(b, x0, a0);
    a1 = mfma32(b, x1, a1);
  }
  __syncthreads();  // drains refill loads; h reads complete before overwrite
  epiW<RELU>(h, a0, 0, w, bias, lr, lh);
  epiW<RELU>(h, a1, 1, w, bias, lr, lh);
  __syncthreads();
}

__global__ __launch_bounds__(512, 4) void nerf_kernel(Params P) {
  __shared__ __align__(16) h16 h[32 * 512];   // 32 KB, frag-major [rt*16 + kt]
  __shared__ __align__(16) h16 ep[8 * 512];   // 8 KB, frag-major [rt*4 + kt]
  __shared__ __align__(16) h16 evp[32];       // 1 ray
  __shared__ float alpha_s[64];

  const int tid = threadIdx.x;
  const int w = tid >> 6, l = tid & 63;
  const int lr = l & 31, lh = l >> 5;
  const int ray = blockIdx.x;
  const h16* wf = P.wf;

  // fill the weight ring with L0's frags immediately (overlaps embed compute)
  half8 wr[4];
#pragma unroll
  for (int j = 0; j < 4; ++j) wr[j] = ldfrag(wf + OFF_P0, j * 8 + w, l);

  // ---- embeddings -> ep (frag-major). thread (s=tid>>3, q=tid&7): 8 cols ----
  {
    const int s = tid >> 3, q = tid & 7;
    const float* ps = P.pts + ((size_t)ray * 64 + s) * 3;
    const float x0 = ps[0], x1 = ps[1], x2 = ps[2];
    half8 v;
#pragma unroll
    for (int j = 0; j < 8; ++j)
      v[j] = (h16)embed_col(q * 8 + j, x0, x1, x2);
    *(half8*)(ep + ((s >> 5) * 4 + (q >> 1)) * 512 + ((s & 31) + 32 * (q & 1)) * 8) = v;
  }
  if (tid < 32) {
    const int idx = tid;
    float v = 0.f;
    if (idx < 27) {
      if (idx < 3) {
        v = P.views[(size_t)ray * 3 + idx];
      } else {
        const int f = (idx - 3) / 6, rem = (idx - 3) % 6, d = rem % 3;
        const float x = P.views[(size_t)ray * 3 + d] * (float)(1 << f);
        v = (rem < 3) ? sinf(x) : cosf(x);
      }
    }
    evp[idx] = (h16)v;
  }
  __syncthreads();

  // ---- L0: K=64 from ep frags; ring refills stream P1's frags 0..3 ----
  {
    f32x16 a0 = (f32x16)0.f, a1 = (f32x16)0.f;
#pragma unroll
    for (int i = 0; i < 4; ++i) {
      half8 x0 = ldsfrag(ep, i, l);
      half8 x1 = ldsfrag(ep, 4 + i, l);
      half8 b = wr[i & 3];
      wr[i & 3] = ldfrag(wf + OFF_P1, i * 8 + w, l);
      a0 = mfma32(b, x0, a0);
      a1 = mfma32(b, x1, a1);
    }
    __syncthreads();
    epiW<true>(h, a0, 0, w, P.pb[0], lr, lh);
    epiW<true>(h, a1, 1, w, P.pb[0], lr, lh);
    __syncthreads();
  }

  // ---- trunk L1..L7 (in-place); ring chains across layers ----
  layerF<16, false, true>(h, ep, wf + OFF_P1, wf + OFF_P2 + (size_t)w * 512, 8, P.pb[1], wr, w, l, lr, lh);
  layerF<16, false, true>(h, ep, wf + OFF_P2, wf + OFF_P3 + (size_t)w * 512, 8, P.pb[2], wr, w, l, lr, lh);
  layerF<16, false, true>(h, ep, wf + OFF_P3, wf + OFF_P4 + (size_t)w * 512, 8, P.pb[3], wr, w, l, lr, lh);
  layerF<16, false, true>(h, ep, wf + OFF_P4, wf + OFF_P5 + (size_t)w * 512, 8, P.pb[4], wr, w, l, lr, lh);
  layerF<20, true,  true>(h, ep, wf + OFF_P5, wf + OFF_P6 + (size_t)w * 512, 8, P.pb[5], wr, w, l, lr, lh);  // K=320 skip
  layerF<16, false, true>(h, ep, wf + OFF_P6, wf + OFF_P7 + (size_t)w * 512, 8, P.pb[6], wr, w, l, lr, lh);
  layerF<16, false, true>(h, ep, wf + OFF_P7, wf + OFF_FEAT + (size_t)w * 512, 8, P.pb[7], wr, w, l, lr, lh);

  // ---- alpha = h @ alpha_w + alpha_b (h stable until FEAT's mid-barrier) ----
  {
    const int s = tid >> 3, q = tid & 7;
    float sum = 0.f;
#pragma unroll
    for (int j = 0; j < 4; ++j) {
      int k0 = q * 32 + j * 8;
      half8 hv = *(const half8*)(h + ((s >> 5) * 16 + (k0 >> 4)) * 512 +
                                 ((s & 31) + 32 * ((k0 >> 3) & 1)) * 8);
      f32x4 w0 = *(const f32x4*)(P.alpha_w + k0);
      f32x4 w1 = *(const f32x4*)(P.alpha_w + k0 + 4);
      sum += (float)hv[0] * w0[0] + (float)hv[1] * w0[1] + (float)hv[2] * w0[2] + (float)hv[3] * w0[3];
      sum += (float)hv[4] * w1[0] + (float)hv[5] * w1[1] + (float)hv[6] * w1[2] + (float)hv[7] * w1[3];
    }
    sum += __shfl_xor(sum, 1);
    sum += __shfl_xor(sum, 2);
    sum += __shfl_xor(sum, 4);
    if (q == 0) alpha_s[s] = sum + P.alpha_b[0];
  }

  // ---- feature = h @ feat_w + feat_b (no relu); ring prefetches VIEWS frags ----
  layerF<16, false, false>(h, ep, wf + OFF_FEAT, wf + OFF_VIEWS + (size_t)(w & 3) * 512, 4, P.feat_b, wr, w, l, lr, lh);

  // ---- h2 = relu([feature, ev] @ views_w + views_b) -> h cols 0..127 ----
  // wave: rt = w>>2, ct = w&3 (18 iterations: 16 h-kt + 2 evp broadcast)
  {
    const int rt = w >> 2, ct = w & 3;
    const h16* wV = wf + OFF_VIEWS;
    f32x16 acc = (f32x16)0.f;
#pragma unroll
    for (int i = 0; i < 18; ++i) {
      half8 x;
      if (i < 16) x = ldsfrag(h, rt * 16 + i, l);
      else x = *(const half8*)(evp + (i - 16) * 16 + lh * 8);  // broadcast row
      half8 b = wr[i & 3];
      if (i + 4 < 18) wr[i & 3] = ldfrag(wV, (i + 4) * 4 + ct, l);
      acc = mfma32(b, x, acc);
    }
    __syncthreads();  // h (feature) reads complete
    epiW<true>(h, acc, rt, ct, P.views_b, lr, lh);
    __syncthreads();
  }

  // ---- rgb + output (all 512 threads) ----
  {
    const int s = tid >> 3, q = tid & 7;
    float r0 = 0.f, r1 = 0.f, r2 = 0.f;
#pragma unroll
    for (int j = 0; j < 2; ++j) {
      int k0 = q * 16 + j * 8;
      half8 hv = *(const half8*)(h + ((s >> 5) * 16 + (k0 >> 4)) * 512 +
                                 ((s & 31) + 32 * ((k0 >> 3) & 1)) * 8);
#pragma unroll
      for (int i = 0; i < 8; ++i) {
        const float f = (float)hv[i];
        r0 += f * P.rgb_w[(k0 + i) * 3 + 0];
        r1 += f * P.rgb_w[(k0 + i) * 3 + 1];
        r2 += f * P.rgb_w[(k0 + i) * 3 + 2];
      }
    }
    r0 += __shfl_xor(r0, 1); r0 += __shfl_xor(r0, 2); r0 += __shfl_xor(r0, 4);
    r1 += __shfl_xor(r1, 1); r1 += __shfl_xor(r1, 2); r1 += __shfl_xor(r1, 4);
    r2 += __shfl_xor(r2, 1); r2 += __shfl_xor(r2, 2); r2 += __shfl_xor(r2, 4);
    if (q == 0) {
      float4 o;
      o.x = r0 + P.rgb_b[0];
      o.y = r1 + P.rgb_b[1];
      o.z = r2 + P.rgb_b[2];
      o.w = alpha_s[s];
      *(float4*)(P.out + ((size_t)ray * 64 + s) * 4) = o;
    }
  }
}

extern "C" void kernel_launch(void* const* d_in, const int* in_sizes, int n_in,
                              void* d_out, int out_size, void* d_ws, size_t ws_size,
                              hipStream_t stream) {
  h16* wsw = (h16*)d_ws;
  auto conv = [&](int idx, int Ksrc, int N, int Kp, int p, int npad, size_t off) {
    int nfrags = (Kp / 16) * (N / 32);
    int total = nfrags * 64;
    convw_kernel<<<(total + 255) / 256, 256, 0, stream>>>(
        (const float*)d_in[idx], wsw + off, Ksrc, N, Kp, p, npad);
  };
  conv(2, 63, 256, 64, 63, 1, OFF_P0);
  conv(4, 256, 256, 256, 256, 0, OFF_P1);
  conv(6, 256, 256, 256, 256, 0, OFF_P2);
  conv(8, 256, 256, 256, 256, 0, OFF_P3);
  conv(10, 256, 256, 256, 256, 0, OFF_P4);
  conv(12, 319, 256, 320, 63, 1, OFF_P5);
  conv(14, 256, 256, 256, 256, 0, OFF_P6);
  conv(16, 256, 256, 256, 256, 0, OFF_P7);
  conv(20, 256, 256, 256, 256, 0, OFF_FEAT);
  conv(18, 283, 128, 288, 283, 5, OFF_VIEWS);

  Params P;
  P.pts = (const float*)d_in[0];
  P.views = (const float*)d_in[1];
  P.wf = wsw;
  for (int i = 0; i < 8; ++i) P.pb[i] = (const float*)d_in[3 + 2 * i];
  P.views_b = (const float*)d_in[19];
  P.feat_b = (const float*)d_in[21];
  P.alpha_w = (const float*)d_in[22];
  P.alpha_b = (const float*)d_in[23];
  P.rgb_w = (const float*)d_in[24];
  P.rgb_b = (const float*)d_in[25];
  P.out = (float*)d_out;

  nerf_kernel<<<4096, 512, 0, stream>>>(P);
}

// Round 13
// 365.541 us; speedup vs baseline: 1.0545x; 1.0123x over previous
//
#include <hip/hip_runtime.h>

typedef _Float16 h16;
typedef __attribute__((ext_vector_type(8))) _Float16 half8;
typedef __attribute__((ext_vector_type(4))) _Float16 half4;
typedef __attribute__((ext_vector_type(4))) float f32x4;
typedef __attribute__((ext_vector_type(16))) float f32x16;

// weight fragment offsets in d_ws (fp16 elements) — identical to R10..R12
constexpr size_t OFF_P0 = 0;        // [64 ][256]
constexpr size_t OFF_P1 = 16384;    // [256][256]
constexpr size_t OFF_P2 = 81920;
constexpr size_t OFF_P3 = 147456;
constexpr size_t OFF_P4 = 212992;
constexpr size_t OFF_P5 = 278528;   // [320][256] (rows 0..63 ep-part w/ zero row 63, 64..319 h-part)
constexpr size_t OFF_P6 = 360448;
constexpr size_t OFF_P7 = 425984;
constexpr size_t OFF_FEAT = 491520; // [256][256]
constexpr size_t OFF_VIEWS = 557056;// [288][128] (zero rows 283..287)

__device__ __forceinline__ f32x16 mfma32(half8 a, half8 b, f32x16 c) {
  return __builtin_amdgcn_mfma_f32_32x32x16_f16(a, b, c, 0, 0, 0);
}
__device__ __forceinline__ half8 ldfrag(const h16* __restrict__ base, int frag, int l) {
  return *(const half8*)(base + (size_t)frag * 512 + (size_t)l * 8);
}
__device__ __forceinline__ half8 ldsfrag(const h16* __restrict__ base, int frag, int l) {
  return *(const half8*)(base + frag * 512 + l * 8);
}

// fp32 [K][N] row-major -> pre-swizzled fp16 fragments for 32x32x16 (unchanged).
__global__ void convw_kernel(const float* __restrict__ src, h16* __restrict__ dst,
                             int Ksrc, int N, int Kp, int p, int npad) {
  int t = blockIdx.x * 256 + threadIdx.x;
  int nfrags = (Kp >> 4) * (N >> 5);
  int frag = t >> 6;
  if (frag >= nfrags) return;
  int l = t & 63;
  int ntiles = N >> 5;
  int kt = frag / ntiles;
  int nt = frag - kt * ntiles;
  int col = nt * 32 + (l & 31);
  int kbase = kt * 16 + (l >> 5) * 8;
  half8 v;
#pragma unroll
  for (int j = 0; j < 8; ++j) {
    int k = kbase + j;
    float x = 0.f;
    if (k < p) {
      x = src[(size_t)k * N + col];
    } else if (k >= p + npad) {
      int r = k - npad;
      if (r < Ksrc) x = src[(size_t)r * N + col];
    }
    v[j] = (h16)x;
  }
  *(half8*)(dst + (size_t)frag * 512 + (size_t)l * 8) = v;
}

struct Params {
  const float* pts;
  const float* views;
  const h16* wf;
  const float* pb[8];
  const float* views_b;
  const float* feat_b;
  const float* alpha_w;
  const float* alpha_b;
  const float* rgb_w;
  const float* rgb_b;
  float* out;
};

// Epilogue: one 32x32 tile -> frag-major LDS (HW-verified R8..R12).
// Element (row,col): frag=(row>>5)*16+(col>>4), slot=(row&31)+32*((col>>3)&1), elem=col&7.
template <bool RELU>
__device__ __forceinline__ void epiW(h16* __restrict__ Y, const f32x16& A,
                                     int rt, int ct, const float* __restrict__ bias,
                                     int lr, int lh) {
#pragma unroll
  for (int g = 0; g < 4; ++g) {
    int col0 = ct * 32 + g * 8 + lh * 4;
    f32x4 bv = *(const f32x4*)(bias + col0);
    half4 pk;
#pragma unroll
    for (int i = 0; i < 4; ++i) {
      float v = A[g * 4 + i] + bv[i];
      if (RELU) v = fmaxf(v, 0.f);
      pk[i] = (h16)v;
    }
    *(half4*)(Y + (rt * 16 + ct * 2 + (g >> 1)) * 512 + ((g & 1) * 32 + lr) * 8 + lh * 4) = pk;
  }
}

// embed value for column c given a point (x0,x1,x2)
__device__ __forceinline__ float embed_col(int c, float x0, float x1, float x2) {
  if (c < 3) return c == 0 ? x0 : (c == 1 ? x1 : x2);
  if (c >= 63) return 0.f;
  int t = c - 3;
  int f = t / 6, rem = t - f * 6;
  int d = rem >= 3 ? rem - 3 : rem;
  float x = (d == 0 ? x0 : (d == 1 ? x1 : x2)) * (float)(1 << f);
  return (rem < 3) ? sinf(x) : cosf(x);
}

// One M=64, N=256 layer, PING-PONG: reads src (frag-major), writes dst.
// Wave w owns col-tile ct=w. Depth-4 weight ring wr[4] as in R12; loop-tail
// refills stream frags 4..KT-1 of wcur then the NEXT layer's frags 0..3.
// Exactly ONE barrier per layer (after the epilogue writes to dst).
// EXTEP (L5, K=320): iterations 0..3 take A from ep; 4..KT-1 from src.
template <int KT, bool EXTEP, bool RELU>
__device__ __forceinline__ void layerP(const h16* __restrict__ src, h16* __restrict__ dst,
                                       const h16* __restrict__ ep,
                                       const h16* __restrict__ wcur,
                                       const h16* __restrict__ wnextp, int nstride,
                                       const float* __restrict__ bias,
                                       half8 (&wr)[4],
                                       int w, int l, int lr, int lh) {
  f32x16 a0 = (f32x16)0.f, a1 = (f32x16)0.f;
#pragma unroll
  for (int i = 0; i < KT; ++i) {
    half8 x0, x1;
    if (EXTEP && i < 4) {
      x0 = ldsfrag(ep, i, l);
      x1 = ldsfrag(ep, 4 + i, l);
    } else {
      const int kt = EXTEP ? i - 4 : i;
      x0 = ldsfrag(src, kt, l);
      x1 = ldsfrag(src, 16 + kt, l);
    }
    half8 b = wr[i & 3];
    if (i + 4 < KT)
      wr[i & 3] = ldfrag(wcur, (i + 4) * 8 + w, l);
    else
      wr[i & 3] = ldfrag(wnextp, (i + 4 - KT) * nstride, l);
    a0 = mfma32(b, x0, a0);
    a1 = mfma32(b, x1, a1);
  }
  // dst != src: epilogue can flow without a pre-barrier
  epiW<RELU>(dst, a0, 0, w, bias, lr, lh);
  epiW<RELU>(dst, a1, 1, w, bias, lr, lh);
  __syncthreads();
}

__global__ __launch_bounds__(512, 4) void nerf_kernel(Params P) {
  __shared__ __align__(16) h16 h0[32 * 512];  // 32 KB, frag-major [rt*16 + kt]
  __shared__ __align__(16) h16 h1[32 * 512];  // 32 KB
  __shared__ __align__(16) h16 ep[8 * 512];   // 8 KB, frag-major [rt*4 + kt]
  __shared__ __align__(16) h16 evp[32];       // 1 ray
  __shared__ float alpha_s[64];

  const int tid = threadIdx.x;
  const int w = tid >> 6, l = tid & 63;
  const int lr = l & 31, lh = l >> 5;
  const int ray = blockIdx.x;
  const h16* wf = P.wf;

  // fill the weight ring with L0's frags immediately (overlaps embed compute)
  half8 wr[4];
#pragma unroll
  for (int j = 0; j < 4; ++j) wr[j] = ldfrag(wf + OFF_P0, j * 8 + w, l);

  // ---- embeddings -> ep (frag-major). thread (s=tid>>3, q=tid&7): 8 cols ----
  {
    const int s = tid >> 3, q = tid & 7;
    const float* ps = P.pts + ((size_t)ray * 64 + s) * 3;
    const float x0 = ps[0], x1 = ps[1], x2 = ps[2];
    half8 v;
#pragma unroll
    for (int j = 0; j < 8; ++j)
      v[j] = (h16)embed_col(q * 8 + j, x0, x1, x2);
    *(half8*)(ep + ((s >> 5) * 4 + (q >> 1)) * 512 + ((s & 31) + 32 * (q & 1)) * 8) = v;
  }
  if (tid < 32) {
    const int idx = tid;
    float v = 0.f;
    if (idx < 27) {
      if (idx < 3) {
        v = P.views[(size_t)ray * 3 + idx];
      } else {
        const int f = (idx - 3) / 6, rem = (idx - 3) % 6, d = rem % 3;
        const float x = P.views[(size_t)ray * 3 + d] * (float)(1 << f);
        v = (rem < 3) ? sinf(x) : cosf(x);
      }
    }
    evp[idx] = (h16)v;
  }
  __syncthreads();

  // ---- L0: K=64 from ep frags -> h0; ring refills stream P1's frags 0..3 ----
  {
    f32x16 a0 = (f32x16)0.f, a1 = (f32x16)0.f;
#pragma unroll
    for (int i = 0; i < 4; ++i) {
      half8 x0 = ldsfrag(ep, i, l);
      half8 x1 = ldsfrag(ep, 4 + i, l);
      half8 b = wr[i & 3];
      wr[i & 3] = ldfrag(wf + OFF_P1, i * 8 + w, l);
      a0 = mfma32(b, x0, a0);
      a1 = mfma32(b, x1, a1);
    }
    epiW<true>(h0, a0, 0, w, P.pb[0], lr, lh);
    epiW<true>(h0, a1, 1, w, P.pb[0], lr, lh);
    __syncthreads();
  }

  // ---- trunk L1..L7 (ping-pong, 1 barrier/layer); ring chains across layers ----
  layerP<16, false, true>(h0, h1, ep, wf + OFF_P1, wf + OFF_P2 + (size_t)w * 512, 8, P.pb[1], wr, w, l, lr, lh);
  layerP<16, false, true>(h1, h0, ep, wf + OFF_P2, wf + OFF_P3 + (size_t)w * 512, 8, P.pb[2], wr, w, l, lr, lh);
  layerP<16, false, true>(h0, h1, ep, wf + OFF_P3, wf + OFF_P4 + (size_t)w * 512, 8, P.pb[3], wr, w, l, lr, lh);
  layerP<16, false, true>(h1, h0, ep, wf + OFF_P4, wf + OFF_P5 + (size_t)w * 512, 8, P.pb[4], wr, w, l, lr, lh);
  layerP<20, true,  true>(h0, h1, ep, wf + OFF_P5, wf + OFF_P6 + (size_t)w * 512, 8, P.pb[5], wr, w, l, lr, lh);  // K=320
  layerP<16, false, true>(h1, h0, ep, wf + OFF_P6, wf + OFF_P7 + (size_t)w * 512, 8, P.pb[6], wr, w, l, lr, lh);
  layerP<16, false, true>(h0, h1, ep, wf + OFF_P7, wf + OFF_FEAT + (size_t)w * 512, 8, P.pb[7], wr, w, l, lr, lh);
  // trunk output now in h1

  // ---- alpha = h1 @ alpha_w + alpha_b (h1 stable until views epilogue) ----
  {
    const int s = tid >> 3, q = tid & 7;
    float sum = 0.f;
#pragma unroll
    for (int j = 0; j < 4; ++j) {
      int k0 = q * 32 + j * 8;
      half8 hv = *(const half8*)(h1 + ((s >> 5) * 16 + (k0 >> 4)) * 512 +
                                 ((s & 31) + 32 * ((k0 >> 3) & 1)) * 8);
      f32x4 w0 = *(const f32x4*)(P.alpha_w + k0);
      f32x4 w1 = *(const f32x4*)(P.alpha_w + k0 + 4);
      sum += (float)hv[0] * w0[0] + (float)hv[1] * w0[1] + (float)hv[2] * w0[2] + (float)hv[3] * w0[3];
      sum += (float)hv[4] * w1[0] + (float)hv[5] * w1[1] + (float)hv[6] * w1[2] + (float)hv[7] * w1[3];
    }
    sum += __shfl_xor(sum, 1);
    sum += __shfl_xor(sum, 2);
    sum += __shfl_xor(sum, 4);
    if (q == 0) alpha_s[s] = sum + P.alpha_b[0];
  }

  // ---- feature = h1 @ feat_w + feat_b (no relu) -> h0; ring prefetches VIEWS ----
  layerP<16, false, false>(h1, h0, ep, wf + OFF_FEAT, wf + OFF_VIEWS + (size_t)(w & 3) * 512, 4, P.feat_b, wr, w, l, lr, lh);

  // ---- h2 = relu([feature, ev] @ views_w + views_b): h0 -> h1 cols 0..127 ----
  // wave: rt = w>>2, ct = w&3 (18 iterations: 16 h-kt + 2 evp broadcast)
  {
    const int rt = w >> 2, ct = w & 3;
    const h16* wV = wf + OFF_VIEWS;
    f32x16 acc = (f32x16)0.f;
#pragma unroll
    for (int i = 0; i < 18; ++i) {
      half8 x;
      if (i < 16) x = ldsfrag(h0, rt * 16 + i, l);
      else x = *(const half8*)(evp + (i - 16) * 16 + lh * 8);  // broadcast row
      half8 b = wr[i & 3];
      if (i + 4 < 18) wr[i & 3] = ldfrag(wV, (i + 4) * 4 + ct, l);
      acc = mfma32(b, x, acc);
    }
    __syncthreads();  // all h1 reads (alpha used h1; FEAT read h1) complete
    epiW<true>(h1, acc, rt, ct, P.views_b, lr, lh);
    __syncthreads();
  }

  // ---- rgb + output (all 512 threads) ----
  {
    const int s = tid >> 3, q = tid & 7;
    float r0 = 0.f, r1 = 0.f, r2 = 0.f;
#pragma unroll
    for (int j = 0; j < 2; ++j) {
      int k0 = q * 16 + j * 8;
      half8 hv = *(const half8*)(h1 + ((s >> 5) * 16 + (k0 >> 4)) * 512 +
                                 ((s & 31) + 32 * ((k0 >> 3) & 1)) * 8);
#pragma unroll
      for (int i = 0; i < 8; ++i) {
        const float f = (float)hv[i];
        r0 += f * P.rgb_w[(k0 + i) * 3 + 0];
        r1 += f * P.rgb_w[(k0 + i) * 3 + 1];
        r2 += f * P.rgb_w[(k0 + i) * 3 + 2];
      }
    }
    r0 += __shfl_xor(r0, 1); r0 += __shfl_xor(r0, 2); r0 += __shfl_xor(r0, 4);
    r1 += __shfl_xor(r1, 1); r1 += __shfl_xor(r1, 2); r1 += __shfl_xor(r1, 4);
    r2 += __shfl_xor(r2, 1); r2 += __shfl_xor(r2, 2); r2 += __shfl_xor(r2, 4);
    if (q == 0) {
      float4 o;
      o.x = r0 + P.rgb_b[0];
      o.y = r1 + P.rgb_b[1];
      o.z = r2 + P.rgb_b[2];
      o.w = alpha_s[s];
      *(float4*)(P.out + ((size_t)ray * 64 + s) * 4) = o;
    }
  }
}

extern "C" void kernel_launch(void* const* d_in, const int* in_sizes, int n_in,
                              void* d_out, int out_size, void* d_ws, size_t ws_size,
                              hipStream_t stream) {
  h16* wsw = (h16*)d_ws;
  auto conv = [&](int idx, int Ksrc, int N, int Kp, int p, int npad, size_t off) {
    int nfrags = (Kp / 16) * (N / 32);
    int total = nfrags * 64;
    convw_kernel<<<(total + 255) / 256, 256, 0, stream>>>(
        (const float*)d_in[idx], wsw + off, Ksrc, N, Kp, p, npad);
  };
  conv(2, 63, 256, 64, 63, 1, OFF_P0);
  conv(4, 256, 256, 256, 256, 0, OFF_P1);
  conv(6, 256, 256, 256, 256, 0, OFF_P2);
  conv(8, 256, 256, 256, 256, 0, OFF_P3);
  conv(10, 256, 256, 256, 256, 0, OFF_P4);
  conv(12, 319, 256, 320, 63, 1, OFF_P5);
  conv(14, 256, 256, 256, 256, 0, OFF_P6);
  conv(16, 256, 256, 256, 256, 0, OFF_P7);
  conv(20, 256, 256, 256, 256, 0, OFF_FEAT);
  conv(18, 283, 128, 288, 283, 5, OFF_VIEWS);

  Params P;
  P.pts = (const float*)d_in[0];
  P.views = (const float*)d_in[1];
  P.wf = wsw;
  for (int i = 0; i < 8; ++i) P.pb[i] = (const float*)d_in[3 + 2 * i];
  P.views_b = (const float*)d_in[19];
  P.feat_b = (const float*)d_in[21];
  P.alpha_w = (const float*)d_in[22];
  P.alpha_b = (const float*)d_in[23];
  P.rgb_w = (const float*)d_in[24];
  P.rgb_b = (const float*)d_in[25];
  P.out = (float*)d_out;

  nerf_kernel<<<4096, 512, 0, stream>>>(P);
}